// Round 6
// baseline (225.077 us; speedup 1.0000x reference)
//
#include <hip/hip_runtime.h>
#include <stdint.h>

#define S_LEN 2048
#define BATCH 2
#define HID 2048
#define NH 16
#define NKV 8
#define HD 128
#define WINDOW 1024
#define SCALE 0.08838834764831845f
#define QKVW 4096

typedef unsigned short u16;
typedef unsigned int u32;
typedef __attribute__((ext_vector_type(8))) short short8;
typedef __attribute__((ext_vector_type(4))) float f32x4;
typedef __attribute__((ext_vector_type(16))) float f32x16;
typedef __attribute__((ext_vector_type(4))) u16 u16x4;

__device__ __forceinline__ u16 f2b(float f) {
  u32 u = __builtin_bit_cast(u32, f);
  return (u16)((u + 0x7fffu + ((u >> 16) & 1u)) >> 16);
}
__device__ __forceinline__ float b2f(u16 h) {
  u32 u = ((u32)h) << 16;
  return __builtin_bit_cast(float, u);
}
__device__ __forceinline__ u32 pk_bf16(float a, float b) {
  u32 d;
  asm("v_cvt_pk_bf16_f32 %0, %1, %2" : "=v"(d) : "v"(a), "v"(b));
  return d;
}

__device__ __forceinline__ void gload_lds16(const u16* g, u16* l) {
  __builtin_amdgcn_global_load_lds(
      (const __attribute__((address_space(1))) u32*)g,
      (__attribute__((address_space(3))) u32*)l, 16, 0, 0);
}

template <int N>
__device__ __forceinline__ void wait_vm() {
  if constexpr (N == 0) asm volatile("s_waitcnt vmcnt(0)" ::: "memory");
  else if constexpr (N == 5) asm volatile("s_waitcnt vmcnt(5)" ::: "memory");
  else if constexpr (N == 6) asm volatile("s_waitcnt vmcnt(6)" ::: "memory");
}

// ---------------- f32 -> bf16 convert ----------------
__global__ __launch_bounds__(256) void k_conv(const float* __restrict__ src,
                                              u16* __restrict__ dst, int n4) {
  int i = blockIdx.x * blockDim.x + threadIdx.x;
  int st = gridDim.x * blockDim.x;
  for (; i < n4; i += st) {
    f32x4 v = ((const f32x4*)src)[i];
    u16x4 o;
    o[0] = f2b(v[0]); o[1] = f2b(v[1]); o[2] = f2b(v[2]); o[3] = f2b(v[3]);
    ((u16x4*)dst)[i] = o;
  }
}

__device__ __forceinline__ void store_c(u16* C, long idx, float v) { C[idx] = f2b(v); }
__device__ __forceinline__ void store_c(float* C, long idx, float v) { C[idx] = v; }

// ---- GEMM C = A*B^T, 256xBN tile, BK=64, 8-phase / 2-K-tile pipeline ----
// REGULAR LEDGER (m201 spec): phase p stages exactly the half-tile whose last
// ds_read was at phase p-1 (1-phase write-after-read gap, barrier-separated);
// every half gets >=3 phases of flight before its legalizing wait. Waits only
// at ph4/ph8: vmcnt(4+BL) leaves the newest 3 half-tiles in flight.
// Reads: ph1:A0,B0  ph2:B1  ph3:A1  ph4:B0  (then same for second K-tile).
// Stages: ph1:B0(u+1)  ph2:A0(u+2)  ph3:B1(u+2)  ph4:A1(u+2)  ph5:B0(u+2)
//         ph6:A0(u+3)  ph7:B1(u+3)  ph8:A1(u+3).
#define LOADAF(BUF, MQ)                                                         \
  _Pragma("unroll") for (int i_ = 0; i_ < 4; ++i_) {                            \
    af[i_][0] = *(const short8*)&sA[BUF][arow + ((MQ)*64 + i_*16) * 64 + akc0]; \
    af[i_][1] = *(const short8*)&sA[BUF][arow + ((MQ)*64 + i_*16) * 64 + akc1]; \
  }
#define LOADBF(BUF, NQ)                                                         \
  _Pragma("unroll") for (int j_ = 0; j_ < NIH; ++j_) {                          \
    bf[j_][0] = *(const short8*)&sB[BUF][brow + ((NQ)*QB + j_*16) * 64 + akc0]; \
    bf[j_][1] = *(const short8*)&sB[BUF][brow + ((NQ)*QB + j_*16) * 64 + akc1]; \
  }
#define STAGE_A(H, BUF, KT)                                            \
  _Pragma("unroll") for (int i_ = 0; i_ < 2; ++i_)                     \
      gload_lds16(Abase + aOff[H][i_] + (KT) * 64, &sA[BUF][aDst[H][i_]]);
#define STAGE_B(H, BUF, KT)                                            \
  _Pragma("unroll") for (int i_ = 0; i_ < BL; ++i_)                    \
      gload_lds16(Bbase + bOff[H][i_] + (KT) * 64, &sB[BUF][bDst[H][i_]]);
#define MFMAQ(MQ, NQ)                                                           \
  __builtin_amdgcn_s_setprio(1);                                                \
  _Pragma("unroll") for (int i_ = 0; i_ < 4; ++i_) {                            \
    _Pragma("unroll") for (int j_ = 0; j_ < NIH; ++j_) {                        \
      acc[(MQ)*4 + i_][(NQ)*NIH + j_] = __builtin_amdgcn_mfma_f32_16x16x32_bf16(\
          af[i_][0], bf[j_][0], acc[(MQ)*4 + i_][(NQ)*NIH + j_], 0, 0, 0);      \
      acc[(MQ)*4 + i_][(NQ)*NIH + j_] = __builtin_amdgcn_mfma_f32_16x16x32_bf16(\
          af[i_][1], bf[j_][1], acc[(MQ)*4 + i_][(NQ)*NIH + j_], 0, 0, 0);      \
    }                                                                           \
  }                                                                             \
  __builtin_amdgcn_s_setprio(0);
#define OPEN_MFMA()                                      \
  __builtin_amdgcn_sched_barrier(0);                     \
  __builtin_amdgcn_s_barrier();                          \
  asm volatile("s_waitcnt lgkmcnt(0)" ::: "memory");     \
  __builtin_amdgcn_sched_barrier(0);
#define CLOSEP()                                         \
  __builtin_amdgcn_s_barrier();                          \
  __builtin_amdgcn_sched_barrier(0);
#define LGKM8()                                          \
  asm volatile("s_waitcnt lgkmcnt(8)" ::: "memory");     \
  __builtin_amdgcn_sched_barrier(0);

template <int BN, typename OutT>
__global__ __launch_bounds__(512, 1) void k_gemm8p(const u16* __restrict__ A,
                                                   const u16* __restrict__ B,
                                                   OutT* __restrict__ C,
                                                   int M, int N, int K) {
  constexpr int NIH = BN / 128;   // bf frags per n-quadrant
  constexpr int NI = 2 * NIH;
  constexpr int BL = BN / 128;    // B gloads per thread per half
  constexpr int QB = BN / 8;      // B interleave block (rows)
  constexpr int WV = 4 + BL;      // leaves 3 newest half-tiles in flight

  __shared__ u16 sA[2][256 * 64];
  __shared__ u16 sB[2][BN * 64];
  const int tid = threadIdx.x;
  const int lane = tid & 63;
  const int w = tid >> 6;
  const int l15 = lane & 15;
  const int lg = lane >> 4;
  const int wm = w >> 2;
  const int wn = w & 3;
  const int sw = l15 & 7;

  const int gx = gridDim.x;
  const int nwg = gx * gridDim.y;
  const int flat = blockIdx.y * gx + blockIdx.x;
  const int tile = (flat & 7) * (nwg >> 3) + (flat >> 3);
  const long m0 = (long)(tile / gx) * 256;
  const long n0 = (long)(tile % gx) * BN;

  const u16* Abase = A + m0 * K;
  const u16* Bbase = B + n0 * K;

  int aOff[2][2], aDst[2][2], bOff[2][2], bDst[2][2];
#pragma unroll
  for (int h = 0; h < 2; ++h) {
#pragma unroll
    for (int i = 0; i < 2; ++i) {
      const int c = tid + i * 512;
      const int lr = c >> 3, chs = c & 7;
      const int grA = ((lr >> 6) << 7) + (h << 6) + (lr & 63);
      aOff[h][i] = grA * K + (chs ^ (grA & 7)) * 8;
      aDst[h][i] = grA * 64 + chs * 8;
    }
#pragma unroll
    for (int i = 0; i < BL; ++i) {
      const int c = tid + i * 512;
      const int lr = c >> 3, chs = c & 7;
      const int grB = (lr / QB) * (2 * QB) + h * QB + (lr % QB);
      bOff[h][i] = grB * K + (chs ^ (grB & 7)) * 8;
      bDst[h][i] = grB * 64 + chs * 8;
    }
  }

  f32x4 acc[8][NI];
  const f32x4 z4 = {0.f, 0.f, 0.f, 0.f};
#pragma unroll
  for (int i = 0; i < 8; ++i)
#pragma unroll
    for (int j = 0; j < NI; ++j) acc[i][j] = z4;

  const int arow = (wm * 128 + l15) * 64;
  const int brow = (wn * (BN / 4) + l15) * 64;
  const int akc0 = (lg ^ sw) * 8;
  const int akc1 = ((4 + lg) ^ sw) * 8;

  const int NT = K >> 6;
  const int NIT = NT >> 1;
  short8 af[4][2], bf[NIH][2];

  // prologue: tile 0 fully + A0(1), B1(1), A1(1); B0(1) staged at ph1.
  STAGE_A(0, 0, 0) STAGE_B(0, 0, 0) STAGE_B(1, 0, 0) STAGE_A(1, 0, 0)
  STAGE_A(0, 1, 1) STAGE_B(1, 1, 1) STAGE_A(1, 1, 1)
  wait_vm<WV>();
  CLOSEP()

  for (int it = 0; it < NIT - 1; ++it) {
    const int u = 2 * it;
    // ph1: tile u (buf0), Q(m-lo,n-lo)
    LOADAF(0, 0) LOADBF(0, 0)
    STAGE_B(0, 1, u + 1)
    LGKM8()
    OPEN_MFMA()
    MFMAQ(0, 0)
    CLOSEP()
    // ph2: Q(m-lo,n-hi)
    LOADBF(0, 1)
    STAGE_A(0, 0, u + 2)
    OPEN_MFMA()
    MFMAQ(0, 1)
    CLOSEP()
    // ph3: Q(m-hi,n-hi)
    LOADAF(0, 1)
    STAGE_B(1, 0, u + 2)
    OPEN_MFMA()
    MFMAQ(1, 1)
    CLOSEP()
    // ph4: Q(m-hi,n-lo); wait legalizes tile u+1 (drains stages >=3 phases old)
    LOADBF(0, 0)
    STAGE_A(1, 0, u + 2)
    wait_vm<WV>();
    OPEN_MFMA()
    MFMAQ(1, 0)
    CLOSEP()
    // ph5: tile u+1 (buf1), Q(m-lo,n-lo)
    LOADAF(1, 0) LOADBF(1, 0)
    STAGE_B(0, 0, u + 2)
    LGKM8()
    OPEN_MFMA()
    MFMAQ(0, 0)
    CLOSEP()
    // ph6
    LOADBF(1, 1)
    STAGE_A(0, 1, u + 3)
    OPEN_MFMA()
    MFMAQ(0, 1)
    CLOSEP()
    // ph7
    LOADAF(1, 1)
    STAGE_B(1, 1, u + 3)
    OPEN_MFMA()
    MFMAQ(1, 1)
    CLOSEP()
    // ph8; wait legalizes tile u+2
    LOADBF(1, 0)
    STAGE_A(1, 1, u + 3)
    wait_vm<WV>();
    OPEN_MFMA()
    MFMAQ(1, 0)
    CLOSEP()
  }
  // peeled last iteration (u = NT-2, NT-1): only B0(NT-1) left to stage
  {
    LOADAF(0, 0) LOADBF(0, 0)
    STAGE_B(0, 1, NT - 1)
    LGKM8()
    OPEN_MFMA()
    MFMAQ(0, 0)
    CLOSEP()
    LOADBF(0, 1)
    OPEN_MFMA()
    MFMAQ(0, 1)
    CLOSEP()
    LOADAF(0, 1)
    OPEN_MFMA()
    MFMAQ(1, 1)
    CLOSEP()
    LOADBF(0, 0)
    wait_vm<0>();
    OPEN_MFMA()
    MFMAQ(1, 0)
    CLOSEP()
    LOADAF(1, 0) LOADBF(1, 0)
    LGKM8()
    OPEN_MFMA()
    MFMAQ(0, 0)
    CLOSEP()
    LOADBF(1, 1)
    OPEN_MFMA()
    MFMAQ(0, 1)
    CLOSEP()
    LOADAF(1, 1)
    OPEN_MFMA()
    MFMAQ(1, 1)
    CLOSEP()
    LOADBF(1, 0)
    OPEN_MFMA()
    MFMAQ(1, 0)
    CLOSEP()
  }

#pragma unroll
  for (int mi = 0; mi < 8; ++mi)
#pragma unroll
    for (int ni = 0; ni < NI; ++ni)
#pragma unroll
      for (int r = 0; r < 4; ++r) {
        long row = m0 + wm * 128 + mi * 16 + lg * 4 + r;
        long col = n0 + wn * (BN / 4) + ni * 16 + l15;
        store_c(C, row * (long)N + col, acc[mi][ni][r]);
      }
}

// ---------------- RMSNorm + RoPE (in place on fused QKV, bf16) ----------------
__global__ __launch_bounds__(256) void k_normrope(u16* __restrict__ QKV,
                                                  const float* __restrict__ cosb,
                                                  const float* __restrict__ sinb,
                                                  const float* __restrict__ qw,
                                                  const float* __restrict__ kw) {
  const int lane = threadIdx.x & 63;
  const int w = threadIdx.x >> 6;
  int row = blockIdx.x * 4 + w;
  const int nQ = BATCH * S_LEN * NH;
  u16* p;
  const float* nw;
  int tok;
  float sc;
  if (row < nQ) {
    tok = row >> 4;
    int h = row & 15;
    p = QKV + (long)tok * QKVW + h * HD;
    nw = qw;
    sc = SCALE;
  } else {
    int r2 = row - nQ;
    tok = r2 >> 3;
    int h = r2 & 7;
    p = QKV + (long)tok * QKVW + 2048 + h * HD;
    nw = kw;
    sc = 1.0f;
  }
  float x0 = b2f(p[lane]);
  float x1 = b2f(p[lane + 64]);
  float ss = x0 * x0 + x1 * x1;
#pragma unroll
  for (int mk = 1; mk < 64; mk <<= 1) ss += __shfl_xor(ss, mk, 64);
  float rinv = rsqrtf(ss * (1.0f / 128.0f) + 1e-6f);
  float y0 = x0 * rinv * nw[lane];
  float y1 = x1 * rinv * nw[lane + 64];
  const float* cp = cosb + (long)tok * HD;
  const float* sp = sinb + (long)tok * HD;
  float o0 = (y0 * cp[lane] - y1 * sp[lane]) * sc;
  float o1 = (y1 * cp[lane + 64] + y0 * sp[lane + 64]) * sc;
  p[lane] = f2b(o0);
  p[lane + 64] = f2b(o1);
}

// ---------------- Flash attention (unchanged) ----------------
__global__ __launch_bounds__(256, 2) void k_attn(const u16* __restrict__ QKV,
                                                 u16* __restrict__ AO) {
  __shared__ u16 sK[64 * 128];
  __shared__ u16 sVT[64 * 128];
  const int tid = threadIdx.x;
  const int lane = tid & 63;
  const int l31 = lane & 31;
  const int hi = lane >> 5;
  const int w = tid >> 6;
  const int q0 = blockIdx.x * 128;
  const int h = blockIdx.y;
  const int b = blockIdx.z;
  const int kvh = h >> 1;
  const int qw0 = q0 + w * 32;
  const int iq = qw0 + l31;

  const long tokbase = (long)b * S_LEN;
  const u16* Qrow = QKV + (tokbase + qw0 + l31) * QKVW + h * HD;
  short8 qf[8];
#pragma unroll
  for (int dt = 0; dt < 8; ++dt) qf[dt] = *(const short8*)(Qrow + dt * 16 + hi * 8);

  f32x16 o[4];
#pragma unroll
  for (int n = 0; n < 4; ++n)
#pragma unroll
    for (int r = 0; r < 16; ++r) o[n][r] = 0.f;
  float m = 0.f, lsum = 0.f;

  const u16* Kbase = QKV + tokbase * QKVW + 2048 + kvh * HD;
  const u16* Vbase = QKV + tokbase * QKVW + 3072 + kvh * HD;

  int kc_row[4], kc_off[4];
  u16* kc_dst[4];
#pragma unroll
  for (int i = 0; i < 4; ++i) {
    const int c = tid + 256 * i;
    kc_row[i] = c >> 4;
    kc_off[i] = (((c & 15) ^ ((c >> 4) & 7))) * 8;
    kc_dst[i] = &sK[c * 8];
  }
  const int rp = tid & 31;
  const int dc0 = tid >> 5;
  const int rg_st = rp >> 2;

  int t_lo = q0 - (WINDOW - 1);
  t_lo = (t_lo < 0 ? 0 : t_lo) >> 6;
  const int t_hi = (q0 + 127) >> 6;

  for (int t = t_lo; t <= t_hi; ++t) {
    const int kv0 = t << 6;
#pragma unroll
    for (int i = 0; i < 4; ++i)
      gload_lds16(Kbase + (long)(kv0 + kc_row[i]) * QKVW + kc_off[i], kc_dst[i]);
#pragma unroll
    for (int i = 0; i < 2; ++i) {
      const int dc = dc0 + i * 8;
      const u16* vp = Vbase + (long)(kv0 + 2 * rp) * QKVW + dc * 8;
      short8 v0 = *(const short8*)vp;
      short8 v1 = *(const short8*)(vp + QKVW);
#pragma unroll
      for (int e = 0; e < 8; ++e) {
        const int d = dc * 8 + e;
        const int unit = d * 8 + (rg_st ^ (d & 7));
        ((u32*)sVT)[unit * 4 + (rp & 3)] = (u32)(u16)v0[e] | ((u32)(u16)v1[e] << 16);
      }
    }
    __syncthreads();

    const bool skipw = (kv0 > qw0 + 31) || (kv0 + 63 < qw0 - (WINDOW - 1));
    if (!skipw) {
      const bool full = (kv0 + 63 <= qw0) && ((qw0 + 31) - kv0 < WINDOW);
      f32x16 s0, s1;
#pragma unroll
      for (int r = 0; r < 16; ++r) { s0[r] = 0.f; s1[r] = 0.f; }
      const int rsw = l31 & 7;
#pragma unroll
      for (int dt = 0; dt < 8; ++dt) {
        const int ch = hi + 2 * dt;
        const short8 kf0 = *(const short8*)&sK[(l31 * 16 + (ch ^ rsw)) * 8];
        s0 = __builtin_amdgcn_mfma_f32_32x32x16_bf16(kf0, qf[dt], s0, 0, 0, 0);
        const short8 kf1 = *(const short8*)&sK[((l31 + 32) * 16 + (ch ^ rsw)) * 8];
        s1 = __builtin_amdgcn_mfma_f32_32x32x16_bf16(kf1, qf[dt], s1, 0, 0, 0);
      }
      float p[32];
#pragma unroll
      for (int r = 0; r < 16; ++r) { p[r] = s0[r]; p[16 + r] = s1[r]; }
      if (!full) {
#pragma unroll
        for (int r = 0; r < 32; ++r) {
          const int kk = kv0 + (r >> 4) * 32 + 4 * hi + (r & 3) + 8 * ((r >> 2) & 3);
          p[r] = ((u32)(iq - kk) < (u32)WINDOW) ? p[r] : -3.0e38f;
        }
      }
      float tm = p[0];
#pragma unroll
      for (int r = 1; r < 32; ++r) tm = fmaxf(tm, p[r]);
      tm = fmaxf(tm, __shfl_xor(tm, 32, 64));
      const float mn = fmaxf(m, tm);
      const float al = __expf(m - mn);
      m = mn;
      float rs = 0.f;
#pragma unroll
      for (int r = 0; r < 32; ++r) { p[r] = __expf(p[r] - mn); rs += p[r]; }
      rs += __shfl_xor(rs, 32, 64);
      lsum = lsum * al + rs;
#pragma unroll
      for (int n = 0; n < 4; ++n)
#pragma unroll
        for (int r = 0; r < 16; ++r) o[n][r] *= al;

      short8 pf[4];
#pragma unroll
      for (int ks = 0; ks < 4; ++ks) {
        const int bb = (ks >> 1) * 16 + (ks & 1) * 8;
        u32 a0 = pk_bf16(p[bb + 0], p[bb + 1]);
        u32 b0 = pk_bf16(p[bb + 4], p[bb + 5]);
        u32 a1 = pk_bf16(p[bb + 2], p[bb + 3]);
        u32 b1 = pk_bf16(p[bb + 6], p[bb + 7]);
        asm volatile("v_permlane32_swap_b32 %0, %1" : "+v"(a0), "+v"(b0));
        asm volatile("v_permlane32_swap_b32 %0, %1" : "+v"(a1), "+v"(b1));
        union { u32 u[4]; short8 s; } uu;
        uu.u[0] = a0; uu.u[1] = a1; uu.u[2] = b0; uu.u[3] = b1;
        pf[ks] = uu.s;
      }
#pragma unroll
      for (int dt = 0; dt < 4; ++dt) {
        const int d = l31 + 32 * dt;
        const int dsw = d & 7;
#pragma unroll
        for (int ks = 0; ks < 4; ++ks) {
          const int rg = ks * 2 + hi;
          const short8 vf = *(const short8*)&sVT[(d * 8 + (rg ^ dsw)) * 8];
          o[dt] = __builtin_amdgcn_mfma_f32_32x32x16_bf16(vf, pf[ks], o[dt], 0, 0, 0);
        }
      }
    }
    __syncthreads();
  }

  __syncthreads();
  float* R = ((float*)sK) + w * 1024;
  const float rl = 1.0f / lsum;
  const int half = hi;
#pragma unroll
  for (int dt = 0; dt < 4; ++dt) {
#pragma unroll
    for (int r = 0; r < 16; ++r) {
      const int dp = 4 * hi + (r & 3) + 8 * (r >> 2);
      R[dp * 32 + (l31 ^ (4 * (dp & 7)))] = o[dt][r] * rl;
    }
    __syncthreads();
    union { u16 hh[16]; short8 s[2]; } U;
#pragma unroll
    for (int j = 0; j < 16; ++j) {
      const int dp = half * 16 + j;
      U.hh[j] = f2b(R[dp * 32 + (l31 ^ (4 * (dp & 7)))]);
    }
    u16* dst = AO + (tokbase + q0 + w * 32 + l31) * (NH * HD) + h * HD + dt * 32 + half * 16;
    *(short8*)dst = U.s[0];
    *(short8*)(dst + 8) = U.s[1];
    __syncthreads();
  }
}

// ---------------- launch ----------------
extern "C" void kernel_launch(void* const* d_in, const int* in_sizes, int n_in,
                              void* d_out, int out_size, void* d_ws, size_t ws_size,
                              hipStream_t stream) {
  const float* hs   = (const float*)d_in[0];
  const float* cosb = (const float*)d_in[1];
  const float* sinb = (const float*)d_in[2];
  const float* Wq   = (const float*)d_in[3];
  const float* Wk   = (const float*)d_in[4];
  const float* Wv   = (const float*)d_in[5];
  const float* Wo   = (const float*)d_in[6];
  const float* qw   = (const float*)d_in[7];
  const float* kw   = (const float*)d_in[8];
  float* out = (float*)d_out;

  const long SZ_X  = (long)BATCH * S_LEN * HID;
  const long SZ_WQ = (long)NH * HD * HID;
  const long SZ_WK = (long)NKV * HD * HID;
  u16* Xb   = (u16*)d_ws;
  u16* Wqb  = Xb + SZ_X;
  u16* Wkb  = Wqb + SZ_WQ;
  u16* Wvb  = Wkb + SZ_WK;
  u16* Wob  = Wvb + SZ_WK;
  u16* QKVb = Wob + SZ_WQ;
  u16* AOb  = QKVb + (long)BATCH * S_LEN * QKVW;

  k_conv<<<2048, 256, 0, stream>>>(hs, Xb, (int)(SZ_X / 4));
  k_conv<<<1024, 256, 0, stream>>>(Wq, Wqb, (int)(SZ_WQ / 4));
  k_conv<<<512, 256, 0, stream>>>(Wk, Wkb, (int)(SZ_WK / 4));
  k_conv<<<512, 256, 0, stream>>>(Wv, Wvb, (int)(SZ_WK / 4));
  k_conv<<<1024, 256, 0, stream>>>(Wo, Wob, (int)(SZ_WQ / 4));

  // fused QKV projection: 4096 x 4096 x 2048, 256 blocks (16x16)
  k_gemm8p<256, u16><<<dim3(16, 16), 512, 0, stream>>>(
      Xb, Wqb, QKVb, BATCH * S_LEN, QKVW, HID);

  k_normrope<<<(BATCH * S_LEN * (NH + NKV)) / 4, 256, 0, stream>>>(QKVb, cosb, sinb, qw, kw);

  k_attn<<<dim3(S_LEN / 128, NH, BATCH), 256, 0, stream>>>(QKVb, AOb);

  // output projection: 4096 x 2048 x 2048, BN=128 -> 256 blocks (16x16)
  k_gemm8p<128, float><<<dim3(16, 16), 512, 0, stream>>>(
      AOb, Wob, out, BATCH * S_LEN, HID, HID);
}

// Round 7
// 223.923 us; speedup vs baseline: 1.0052x; 1.0052x over previous
//
#include <hip/hip_runtime.h>
#include <stdint.h>

#define S_LEN 2048
#define BATCH 2
#define HID 2048
#define NH 16
#define NKV 8
#define HD 128
#define WINDOW 1024
#define SCALE 0.08838834764831845f
#define QKVW 4096

typedef unsigned short u16;
typedef unsigned int u32;
typedef __attribute__((ext_vector_type(8))) short short8;
typedef __attribute__((ext_vector_type(4))) float f32x4;
typedef __attribute__((ext_vector_type(16))) float f32x16;
typedef __attribute__((ext_vector_type(4))) u16 u16x4;

__device__ __forceinline__ u16 f2b(float f) {
  u32 u = __builtin_bit_cast(u32, f);
  return (u16)((u + 0x7fffu + ((u >> 16) & 1u)) >> 16);
}
__device__ __forceinline__ float b2f(u16 h) {
  u32 u = ((u32)h) << 16;
  return __builtin_bit_cast(float, u);
}
__device__ __forceinline__ u32 pk_bf16(float a, float b) {
  u32 d;
  asm("v_cvt_pk_bf16_f32 %0, %1, %2" : "=v"(d) : "v"(a), "v"(b));
  return d;
}

__device__ __forceinline__ void gload_lds16(const u16* g, u16* l) {
  __builtin_amdgcn_global_load_lds(
      (const __attribute__((address_space(1))) u32*)g,
      (__attribute__((address_space(3))) u32*)l, 16, 0, 0);
}

template <int N>
__device__ __forceinline__ void wait_vm() {
  if constexpr (N == 0) asm volatile("s_waitcnt vmcnt(0)" ::: "memory");
  else if constexpr (N == 5) asm volatile("s_waitcnt vmcnt(5)" ::: "memory");
  else if constexpr (N == 6) asm volatile("s_waitcnt vmcnt(6)" ::: "memory");
}

// ---------------- f32 -> bf16 convert ----------------
__global__ __launch_bounds__(256) void k_conv(const float* __restrict__ src,
                                              u16* __restrict__ dst, int n4) {
  int i = blockIdx.x * blockDim.x + threadIdx.x;
  int st = gridDim.x * blockDim.x;
  for (; i < n4; i += st) {
    f32x4 v = ((const f32x4*)src)[i];
    u16x4 o;
    o[0] = f2b(v[0]); o[1] = f2b(v[1]); o[2] = f2b(v[2]); o[3] = f2b(v[3]);
    ((u16x4*)dst)[i] = o;
  }
}

__device__ __forceinline__ void store_c(u16* C, long idx, float v) { C[idx] = f2b(v); }
__device__ __forceinline__ void store_c(float* C, long idx, float v) { C[idx] = v; }

// ---- GEMM C = A*B^T, 256xBN tile, BK=64, 8-phase / 2-K-tile pipeline ----
// Regular ledger (round 5); round 7 change: NO forced lgkmcnt(0) before the
// MFMA cluster. ds_reads are C++ loads -> compiler emits fine-grained
// lgkmcnt(N) per consuming MFMA, so early MFMAs overlap LDS completion of
// later fragments (the m97/m201 mechanism). Phase boundaries stay fenced by
// sched_barrier(0)+s_barrier on both sides; every loaded value is consumed
// in-phase, so all reads complete before the closing barrier (ledger's
// write-after-read guard is preserved).
#define LOADAF(BUF, MQ)                                                         \
  _Pragma("unroll") for (int i_ = 0; i_ < 4; ++i_) {                            \
    af[i_][0] = *(const short8*)&sA[BUF][arow + ((MQ)*64 + i_*16) * 64 + akc0]; \
    af[i_][1] = *(const short8*)&sA[BUF][arow + ((MQ)*64 + i_*16) * 64 + akc1]; \
  }
#define LOADBF(BUF, NQ)                                                         \
  _Pragma("unroll") for (int j_ = 0; j_ < NIH; ++j_) {                          \
    bf[j_][0] = *(const short8*)&sB[BUF][brow + ((NQ)*QB + j_*16) * 64 + akc0]; \
    bf[j_][1] = *(const short8*)&sB[BUF][brow + ((NQ)*QB + j_*16) * 64 + akc1]; \
  }
#define STAGE_A(H, BUF, KT)                                            \
  _Pragma("unroll") for (int i_ = 0; i_ < 2; ++i_)                     \
      gload_lds16(Abase + aOff[H][i_] + (KT) * 64, &sA[BUF][aDst[H][i_]]);
#define STAGE_B(H, BUF, KT)                                            \
  _Pragma("unroll") for (int i_ = 0; i_ < BL; ++i_)                    \
      gload_lds16(Bbase + bOff[H][i_] + (KT) * 64, &sB[BUF][bDst[H][i_]]);
#define MFMAQ(MQ, NQ)                                                           \
  __builtin_amdgcn_s_setprio(1);                                                \
  _Pragma("unroll") for (int i_ = 0; i_ < 4; ++i_) {                            \
    _Pragma("unroll") for (int j_ = 0; j_ < NIH; ++j_) {                        \
      acc[(MQ)*4 + i_][(NQ)*NIH + j_] = __builtin_amdgcn_mfma_f32_16x16x32_bf16(\
          af[i_][0], bf[j_][0], acc[(MQ)*4 + i_][(NQ)*NIH + j_], 0, 0, 0);      \
      acc[(MQ)*4 + i_][(NQ)*NIH + j_] = __builtin_amdgcn_mfma_f32_16x16x32_bf16(\
          af[i_][1], bf[j_][1], acc[(MQ)*4 + i_][(NQ)*NIH + j_], 0, 0, 0);      \
    }                                                                           \
  }                                                                             \
  __builtin_amdgcn_s_setprio(0);
#define OPENP()                                          \
  __builtin_amdgcn_sched_barrier(0);                     \
  __builtin_amdgcn_s_barrier();                          \
  __builtin_amdgcn_sched_barrier(0);
#define CLOSEP()                                         \
  __builtin_amdgcn_s_barrier();                          \
  __builtin_amdgcn_sched_barrier(0);

template <int BN, typename OutT>
__global__ __launch_bounds__(512, 1) void k_gemm8p(const u16* __restrict__ A,
                                                   const u16* __restrict__ B,
                                                   OutT* __restrict__ C,
                                                   int M, int N, int K) {
  constexpr int NIH = BN / 128;   // bf frags per n-quadrant
  constexpr int NI = 2 * NIH;
  constexpr int BL = BN / 128;    // B gloads per thread per half
  constexpr int QB = BN / 8;      // B interleave block (rows)
  constexpr int WV = 4 + BL;      // leaves 3 newest half-tiles in flight

  __shared__ u16 sA[2][256 * 64];
  __shared__ u16 sB[2][BN * 64];
  const int tid = threadIdx.x;
  const int lane = tid & 63;
  const int w = tid >> 6;
  const int l15 = lane & 15;
  const int lg = lane >> 4;
  const int wm = w >> 2;
  const int wn = w & 3;
  const int sw = l15 & 7;

  const int gx = gridDim.x;
  const int nwg = gx * gridDim.y;
  const int flat = blockIdx.y * gx + blockIdx.x;
  const int tile = (flat & 7) * (nwg >> 3) + (flat >> 3);
  const long m0 = (long)(tile / gx) * 256;
  const long n0 = (long)(tile % gx) * BN;

  const u16* Abase = A + m0 * K;
  const u16* Bbase = B + n0 * K;

  int aOff[2][2], aDst[2][2], bOff[2][2], bDst[2][2];
#pragma unroll
  for (int h = 0; h < 2; ++h) {
#pragma unroll
    for (int i = 0; i < 2; ++i) {
      const int c = tid + i * 512;
      const int lr = c >> 3, chs = c & 7;
      const int grA = ((lr >> 6) << 7) + (h << 6) + (lr & 63);
      aOff[h][i] = grA * K + (chs ^ (grA & 7)) * 8;
      aDst[h][i] = grA * 64 + chs * 8;
    }
#pragma unroll
    for (int i = 0; i < BL; ++i) {
      const int c = tid + i * 512;
      const int lr = c >> 3, chs = c & 7;
      const int grB = (lr / QB) * (2 * QB) + h * QB + (lr % QB);
      bOff[h][i] = grB * K + (chs ^ (grB & 7)) * 8;
      bDst[h][i] = grB * 64 + chs * 8;
    }
  }

  f32x4 acc[8][NI];
  const f32x4 z4 = {0.f, 0.f, 0.f, 0.f};
#pragma unroll
  for (int i = 0; i < 8; ++i)
#pragma unroll
    for (int j = 0; j < NI; ++j) acc[i][j] = z4;

  const int arow = (wm * 128 + l15) * 64;
  const int brow = (wn * (BN / 4) + l15) * 64;
  const int akc0 = (lg ^ sw) * 8;
  const int akc1 = ((4 + lg) ^ sw) * 8;

  const int NT = K >> 6;
  const int NIT = NT >> 1;
  short8 af[4][2], bf[NIH][2];

  // prologue: tile 0 fully + A0(1), B1(1), A1(1); B0(1) staged at ph1.
  STAGE_A(0, 0, 0) STAGE_B(0, 0, 0) STAGE_B(1, 0, 0) STAGE_A(1, 0, 0)
  STAGE_A(0, 1, 1) STAGE_B(1, 1, 1) STAGE_A(1, 1, 1)
  wait_vm<WV>();
  CLOSEP()

  for (int it = 0; it < NIT - 1; ++it) {
    const int u = 2 * it;
    // ph1: tile u (buf0), Q(m-lo,n-lo)
    LOADBF(0, 0) LOADAF(0, 0)
    STAGE_B(0, 1, u + 1)
    OPENP()
    MFMAQ(0, 0)
    CLOSEP()
    // ph2: Q(m-lo,n-hi)
    LOADBF(0, 1)
    STAGE_A(0, 0, u + 2)
    OPENP()
    MFMAQ(0, 1)
    CLOSEP()
    // ph3: Q(m-hi,n-hi)
    LOADAF(0, 1)
    STAGE_B(1, 0, u + 2)
    OPENP()
    MFMAQ(1, 1)
    CLOSEP()
    // ph4: Q(m-hi,n-lo); wait legalizes tile u+1
    LOADBF(0, 0)
    STAGE_A(1, 0, u + 2)
    wait_vm<WV>();
    OPENP()
    MFMAQ(1, 0)
    CLOSEP()
    // ph5: tile u+1 (buf1), Q(m-lo,n-lo)
    LOADBF(1, 0) LOADAF(1, 0)
    STAGE_B(0, 0, u + 2)
    OPENP()
    MFMAQ(0, 0)
    CLOSEP()
    // ph6
    LOADBF(1, 1)
    STAGE_A(0, 1, u + 3)
    OPENP()
    MFMAQ(0, 1)
    CLOSEP()
    // ph7
    LOADAF(1, 1)
    STAGE_B(1, 1, u + 3)
    OPENP()
    MFMAQ(1, 1)
    CLOSEP()
    // ph8; wait legalizes tile u+2
    LOADBF(1, 0)
    STAGE_A(1, 1, u + 3)
    wait_vm<WV>();
    OPENP()
    MFMAQ(1, 0)
    CLOSEP()
  }
  // peeled last iteration (u = NT-2, NT-1): only B0(NT-1) left to stage
  {
    LOADBF(0, 0) LOADAF(0, 0)
    STAGE_B(0, 1, NT - 1)
    OPENP()
    MFMAQ(0, 0)
    CLOSEP()
    LOADBF(0, 1)
    OPENP()
    MFMAQ(0, 1)
    CLOSEP()
    LOADAF(0, 1)
    OPENP()
    MFMAQ(1, 1)
    CLOSEP()
    LOADBF(0, 0)
    wait_vm<0>();
    OPENP()
    MFMAQ(1, 0)
    CLOSEP()
    LOADBF(1, 0) LOADAF(1, 0)
    OPENP()
    MFMAQ(0, 0)
    CLOSEP()
    LOADBF(1, 1)
    OPENP()
    MFMAQ(0, 1)
    CLOSEP()
    LOADAF(1, 1)
    OPENP()
    MFMAQ(1, 1)
    CLOSEP()
    LOADBF(1, 0)
    OPENP()
    MFMAQ(1, 0)
    CLOSEP()
  }

#pragma unroll
  for (int mi = 0; mi < 8; ++mi)
#pragma unroll
    for (int ni = 0; ni < NI; ++ni)
#pragma unroll
      for (int r = 0; r < 4; ++r) {
        long row = m0 + wm * 128 + mi * 16 + lg * 4 + r;
        long col = n0 + wn * (BN / 4) + ni * 16 + l15;
        store_c(C, row * (long)N + col, acc[mi][ni][r]);
      }
}

// ---------------- RMSNorm + RoPE (in place on fused QKV, bf16) ----------------
__global__ __launch_bounds__(256) void k_normrope(u16* __restrict__ QKV,
                                                  const float* __restrict__ cosb,
                                                  const float* __restrict__ sinb,
                                                  const float* __restrict__ qw,
                                                  const float* __restrict__ kw) {
  const int lane = threadIdx.x & 63;
  const int w = threadIdx.x >> 6;
  int row = blockIdx.x * 4 + w;
  const int nQ = BATCH * S_LEN * NH;
  u16* p;
  const float* nw;
  int tok;
  float sc;
  if (row < nQ) {
    tok = row >> 4;
    int h = row & 15;
    p = QKV + (long)tok * QKVW + h * HD;
    nw = qw;
    sc = SCALE;
  } else {
    int r2 = row - nQ;
    tok = r2 >> 3;
    int h = r2 & 7;
    p = QKV + (long)tok * QKVW + 2048 + h * HD;
    nw = kw;
    sc = 1.0f;
  }
  float x0 = b2f(p[lane]);
  float x1 = b2f(p[lane + 64]);
  float ss = x0 * x0 + x1 * x1;
#pragma unroll
  for (int mk = 1; mk < 64; mk <<= 1) ss += __shfl_xor(ss, mk, 64);
  float rinv = rsqrtf(ss * (1.0f / 128.0f) + 1e-6f);
  float y0 = x0 * rinv * nw[lane];
  float y1 = x1 * rinv * nw[lane + 64];
  const float* cp = cosb + (long)tok * HD;
  const float* sp = sinb + (long)tok * HD;
  float o0 = (y0 * cp[lane] - y1 * sp[lane]) * sc;
  float o1 = (y1 * cp[lane + 64] + y0 * sp[lane + 64]) * sc;
  p[lane] = f2b(o0);
  p[lane + 64] = f2b(o1);
}

// ---------------- Flash attention (unchanged) ----------------
__global__ __launch_bounds__(256, 2) void k_attn(const u16* __restrict__ QKV,
                                                 u16* __restrict__ AO) {
  __shared__ u16 sK[64 * 128];
  __shared__ u16 sVT[64 * 128];
  const int tid = threadIdx.x;
  const int lane = tid & 63;
  const int l31 = lane & 31;
  const int hi = lane >> 5;
  const int w = tid >> 6;
  const int q0 = blockIdx.x * 128;
  const int h = blockIdx.y;
  const int b = blockIdx.z;
  const int kvh = h >> 1;
  const int qw0 = q0 + w * 32;
  const int iq = qw0 + l31;

  const long tokbase = (long)b * S_LEN;
  const u16* Qrow = QKV + (tokbase + qw0 + l31) * QKVW + h * HD;
  short8 qf[8];
#pragma unroll
  for (int dt = 0; dt < 8; ++dt) qf[dt] = *(const short8*)(Qrow + dt * 16 + hi * 8);

  f32x16 o[4];
#pragma unroll
  for (int n = 0; n < 4; ++n)
#pragma unroll
    for (int r = 0; r < 16; ++r) o[n][r] = 0.f;
  float m = 0.f, lsum = 0.f;

  const u16* Kbase = QKV + tokbase * QKVW + 2048 + kvh * HD;
  const u16* Vbase = QKV + tokbase * QKVW + 3072 + kvh * HD;

  int kc_row[4], kc_off[4];
  u16* kc_dst[4];
#pragma unroll
  for (int i = 0; i < 4; ++i) {
    const int c = tid + 256 * i;
    kc_row[i] = c >> 4;
    kc_off[i] = (((c & 15) ^ ((c >> 4) & 7))) * 8;
    kc_dst[i] = &sK[c * 8];
  }
  const int rp = tid & 31;
  const int dc0 = tid >> 5;
  const int rg_st = rp >> 2;

  int t_lo = q0 - (WINDOW - 1);
  t_lo = (t_lo < 0 ? 0 : t_lo) >> 6;
  const int t_hi = (q0 + 127) >> 6;

  for (int t = t_lo; t <= t_hi; ++t) {
    const int kv0 = t << 6;
#pragma unroll
    for (int i = 0; i < 4; ++i)
      gload_lds16(Kbase + (long)(kv0 + kc_row[i]) * QKVW + kc_off[i], kc_dst[i]);
#pragma unroll
    for (int i = 0; i < 2; ++i) {
      const int dc = dc0 + i * 8;
      const u16* vp = Vbase + (long)(kv0 + 2 * rp) * QKVW + dc * 8;
      short8 v0 = *(const short8*)vp;
      short8 v1 = *(const short8*)(vp + QKVW);
#pragma unroll
      for (int e = 0; e < 8; ++e) {
        const int d = dc * 8 + e;
        const int unit = d * 8 + (rg_st ^ (d & 7));
        ((u32*)sVT)[unit * 4 + (rp & 3)] = (u32)(u16)v0[e] | ((u32)(u16)v1[e] << 16);
      }
    }
    __syncthreads();

    const bool skipw = (kv0 > qw0 + 31) || (kv0 + 63 < qw0 - (WINDOW - 1));
    if (!skipw) {
      const bool full = (kv0 + 63 <= qw0) && ((qw0 + 31) - kv0 < WINDOW);
      f32x16 s0, s1;
#pragma unroll
      for (int r = 0; r < 16; ++r) { s0[r] = 0.f; s1[r] = 0.f; }
      const int rsw = l31 & 7;
#pragma unroll
      for (int dt = 0; dt < 8; ++dt) {
        const int ch = hi + 2 * dt;
        const short8 kf0 = *(const short8*)&sK[(l31 * 16 + (ch ^ rsw)) * 8];
        s0 = __builtin_amdgcn_mfma_f32_32x32x16_bf16(kf0, qf[dt], s0, 0, 0, 0);
        const short8 kf1 = *(const short8*)&sK[((l31 + 32) * 16 + (ch ^ rsw)) * 8];
        s1 = __builtin_amdgcn_mfma_f32_32x32x16_bf16(kf1, qf[dt], s1, 0, 0, 0);
      }
      float p[32];
#pragma unroll
      for (int r = 0; r < 16; ++r) { p[r] = s0[r]; p[16 + r] = s1[r]; }
      if (!full) {
#pragma unroll
        for (int r = 0; r < 32; ++r) {
          const int kk = kv0 + (r >> 4) * 32 + 4 * hi + (r & 3) + 8 * ((r >> 2) & 3);
          p[r] = ((u32)(iq - kk) < (u32)WINDOW) ? p[r] : -3.0e38f;
        }
      }
      float tm = p[0];
#pragma unroll
      for (int r = 1; r < 32; ++r) tm = fmaxf(tm, p[r]);
      tm = fmaxf(tm, __shfl_xor(tm, 32, 64));
      const float mn = fmaxf(m, tm);
      const float al = __expf(m - mn);
      m = mn;
      float rs = 0.f;
#pragma unroll
      for (int r = 0; r < 32; ++r) { p[r] = __expf(p[r] - mn); rs += p[r]; }
      rs += __shfl_xor(rs, 32, 64);
      lsum = lsum * al + rs;
#pragma unroll
      for (int n = 0; n < 4; ++n)
#pragma unroll
        for (int r = 0; r < 16; ++r) o[n][r] *= al;

      short8 pf[4];
#pragma unroll
      for (int ks = 0; ks < 4; ++ks) {
        const int bb = (ks >> 1) * 16 + (ks & 1) * 8;
        u32 a0 = pk_bf16(p[bb + 0], p[bb + 1]);
        u32 b0 = pk_bf16(p[bb + 4], p[bb + 5]);
        u32 a1 = pk_bf16(p[bb + 2], p[bb + 3]);
        u32 b1 = pk_bf16(p[bb + 6], p[bb + 7]);
        asm volatile("v_permlane32_swap_b32 %0, %1" : "+v"(a0), "+v"(b0));
        asm volatile("v_permlane32_swap_b32 %0, %1" : "+v"(a1), "+v"(b1));
        union { u32 u[4]; short8 s; } uu;
        uu.u[0] = a0; uu.u[1] = a1; uu.u[2] = b0; uu.u[3] = b1;
        pf[ks] = uu.s;
      }
#pragma unroll
      for (int dt = 0; dt < 4; ++dt) {
        const int d = l31 + 32 * dt;
        const int dsw = d & 7;
#pragma unroll
        for (int ks = 0; ks < 4; ++ks) {
          const int rg = ks * 2 + hi;
          const short8 vf = *(const short8*)&sVT[(d * 8 + (rg ^ dsw)) * 8];
          o[dt] = __builtin_amdgcn_mfma_f32_32x32x16_bf16(vf, pf[ks], o[dt], 0, 0, 0);
        }
      }
    }
    __syncthreads();
  }

  __syncthreads();
  float* R = ((float*)sK) + w * 1024;
  const float rl = 1.0f / lsum;
  const int half = hi;
#pragma unroll
  for (int dt = 0; dt < 4; ++dt) {
#pragma unroll
    for (int r = 0; r < 16; ++r) {
      const int dp = 4 * hi + (r & 3) + 8 * (r >> 2);
      R[dp * 32 + (l31 ^ (4 * (dp & 7)))] = o[dt][r] * rl;
    }
    __syncthreads();
    union { u16 hh[16]; short8 s[2]; } U;
#pragma unroll
    for (int j = 0; j < 16; ++j) {
      const int dp = half * 16 + j;
      U.hh[j] = f2b(R[dp * 32 + (l31 ^ (4 * (dp & 7)))]);
    }
    u16* dst = AO + (tokbase + q0 + w * 32 + l31) * (NH * HD) + h * HD + dt * 32 + half * 16;
    *(short8*)dst = U.s[0];
    *(short8*)(dst + 8) = U.s[1];
    __syncthreads();
  }
}

// ---------------- launch ----------------
extern "C" void kernel_launch(void* const* d_in, const int* in_sizes, int n_in,
                              void* d_out, int out_size, void* d_ws, size_t ws_size,
                              hipStream_t stream) {
  const float* hs   = (const float*)d_in[0];
  const float* cosb = (const float*)d_in[1];
  const float* sinb = (const float*)d_in[2];
  const float* Wq   = (const float*)d_in[3];
  const float* Wk   = (const float*)d_in[4];
  const float* Wv   = (const float*)d_in[5];
  const float* Wo   = (const float*)d_in[6];
  const float* qw   = (const float*)d_in[7];
  const float* kw   = (const float*)d_in[8];
  float* out = (float*)d_out;

  const long SZ_X  = (long)BATCH * S_LEN * HID;
  const long SZ_WQ = (long)NH * HD * HID;
  const long SZ_WK = (long)NKV * HD * HID;
  u16* Xb   = (u16*)d_ws;
  u16* Wqb  = Xb + SZ_X;
  u16* Wkb  = Wqb + SZ_WQ;
  u16* Wvb  = Wkb + SZ_WK;
  u16* Wob  = Wvb + SZ_WK;
  u16* QKVb = Wob + SZ_WQ;
  u16* AOb  = QKVb + (long)BATCH * S_LEN * QKVW;

  k_conv<<<2048, 256, 0, stream>>>(hs, Xb, (int)(SZ_X / 4));
  k_conv<<<1024, 256, 0, stream>>>(Wq, Wqb, (int)(SZ_WQ / 4));
  k_conv<<<512, 256, 0, stream>>>(Wk, Wkb, (int)(SZ_WK / 4));
  k_conv<<<512, 256, 0, stream>>>(Wv, Wvb, (int)(SZ_WK / 4));
  k_conv<<<1024, 256, 0, stream>>>(Wo, Wob, (int)(SZ_WQ / 4));

  // fused QKV projection: 4096 x 4096 x 2048, 256 blocks (16x16)
  k_gemm8p<256, u16><<<dim3(16, 16), 512, 0, stream>>>(
      Xb, Wqb, QKVb, BATCH * S_LEN, QKVW, HID);

  k_normrope<<<(BATCH * S_LEN * (NH + NKV)) / 4, 256, 0, stream>>>(QKVb, cosb, sinb, qw, kw);

  k_attn<<<dim3(S_LEN / 128, NH, BATCH), 256, 0, stream>>>(QKVb, AOb);

  // output projection: 4096 x 2048 x 2048, BN=128 -> 256 blocks (16x16)
  k_gemm8p<128, float><<<dim3(16, 16), 512, 0, stream>>>(
      AOb, Wob, out, BATCH * S_LEN, HID, HID);
}

// Round 8
// 213.637 us; speedup vs baseline: 1.0535x; 1.0481x over previous
//
#include <hip/hip_runtime.h>
#include <stdint.h>

#define S_LEN 2048
#define BATCH 2
#define HID 2048
#define NH 16
#define NKV 8
#define HD 128
#define WINDOW 1024
#define SCALE 0.08838834764831845f
#define QKVW 4096

typedef unsigned short u16;
typedef unsigned int u32;
typedef __attribute__((ext_vector_type(8))) short short8;
typedef __attribute__((ext_vector_type(4))) float f32x4;
typedef __attribute__((ext_vector_type(16))) float f32x16;
typedef __attribute__((ext_vector_type(4))) u16 u16x4;

__device__ __forceinline__ u16 f2b(float f) {
  u32 u = __builtin_bit_cast(u32, f);
  return (u16)((u + 0x7fffu + ((u >> 16) & 1u)) >> 16);
}
__device__ __forceinline__ float b2f(u16 h) {
  u32 u = ((u32)h) << 16;
  return __builtin_bit_cast(float, u);
}
__device__ __forceinline__ u32 pk_bf16(float a, float b) {
  u32 d;
  asm("v_cvt_pk_bf16_f32 %0, %1, %2" : "=v"(d) : "v"(a), "v"(b));
  return d;
}

__device__ __forceinline__ void gload_lds16(const u16* g, u16* l) {
  __builtin_amdgcn_global_load_lds(
      (const __attribute__((address_space(1))) u32*)g,
      (__attribute__((address_space(3))) u32*)l, 16, 0, 0);
}

template <int N>
__device__ __forceinline__ void wait_vm() {
  if constexpr (N == 0) asm volatile("s_waitcnt vmcnt(0)" ::: "memory");
  else if constexpr (N == 8) asm volatile("s_waitcnt vmcnt(8)" ::: "memory");
}

// ---------------- f32 -> bf16 convert ----------------
__global__ __launch_bounds__(256) void k_conv(const float* __restrict__ src,
                                              u16* __restrict__ dst, int n4) {
  int i = blockIdx.x * blockDim.x + threadIdx.x;
  int st = gridDim.x * blockDim.x;
  for (; i < n4; i += st) {
    f32x4 v = ((const f32x4*)src)[i];
    u16x4 o;
    o[0] = f2b(v[0]); o[1] = f2b(v[1]); o[2] = f2b(v[2]); o[3] = f2b(v[3]);
    ((u16x4*)dst)[i] = o;
  }
}

__device__ __forceinline__ void store_c(u16* C, long idx, float v) { C[idx] = f2b(v); }
__device__ __forceinline__ void store_c(float* C, long idx, float v) { C[idx] = v; }

// ---- GEMM C = A*B^T : 128x128 tile, BK=64, 2 blocks/CU (TLP pipeline) ----
// 256 threads = 4 waves (2x2), per-wave 64x64 output. 64 KB LDS dbuf ->
// 2 resident blocks per CU: when one block sits at its barrier/vmcnt, the
// other block's waves feed the MFMA + LDS pipes (m114 cross-block overlap).
// One stage (8 gload_lds) per K-tile, full-K-tile prefetch lead, counted
// vmcnt(8) (never 0 mid-loop), two raw s_barriers per K-tile, fine-grained
// compiler lgkm waits inside the read+MFMA body.
template <typename OutT>
__global__ __launch_bounds__(256, 2) void k_gemm2b(const u16* __restrict__ A,
                                                   const u16* __restrict__ B,
                                                   OutT* __restrict__ C,
                                                   int M, int N, int K) {
  __shared__ u16 sA[2][128 * 64];
  __shared__ u16 sB[2][128 * 64];
  const int tid = threadIdx.x;
  const int lane = tid & 63;
  const int w = tid >> 6;
  const int l15 = lane & 15;
  const int lg = lane >> 4;
  const int wm = w >> 1;
  const int wn = w & 1;
  const int sw = l15 & 7;

  const int gx = gridDim.x;
  const int nwg = gx * gridDim.y;
  const int flat = blockIdx.y * gx + blockIdx.x;
  const int tile = (flat & 7) * (nwg >> 3) + (flat >> 3);
  const long m0 = (long)(tile / gx) * 128;
  const long n0 = (long)(tile % gx) * 128;

  const u16* Abase = A + m0 * K;
  const u16* Bbase = B + n0 * K;

  // staging: 1024 chunks of 16B per matrix per K-tile; 4 A + 4 B per thread.
  // LDS linear (wave-uniform base + lane*16), global source inverse-swizzled.
  int aOff[4], bOff[4], dstOff[4];
#pragma unroll
  for (int i = 0; i < 4; ++i) {
    const int c = tid + i * 256;
    const int row = c >> 3, chs = c & 7;
    const int scol = (chs ^ (row & 7)) * 8;
    aOff[i] = row * K + scol;
    bOff[i] = row * K + scol;
    dstOff[i] = c * 8;
  }

  f32x4 acc[4][4];
  const f32x4 z4 = {0.f, 0.f, 0.f, 0.f};
#pragma unroll
  for (int i = 0; i < 4; ++i)
#pragma unroll
    for (int j = 0; j < 4; ++j) acc[i][j] = z4;

  const int arow = (wm * 64 + l15) * 64;
  const int brow = (wn * 64 + l15) * 64;
  const int akc0 = (lg ^ sw) * 8;
  const int akc1 = ((4 + lg) ^ sw) * 8;

  const int NT = K >> 6;

#define STG(KT, BUF)                                                     \
  _Pragma("unroll") for (int i_ = 0; i_ < 4; ++i_)                       \
      gload_lds16(Abase + aOff[i_] + (KT) * 64, &sA[BUF][dstOff[i_]]);   \
  _Pragma("unroll") for (int i_ = 0; i_ < 4; ++i_)                       \
      gload_lds16(Bbase + bOff[i_] + (KT) * 64, &sB[BUF][dstOff[i_]]);

  STG(0, 0)                      // prologue: tile 0 -> buf 0

  for (int t = 0; t < NT; ++t) {
    const int cur = t & 1;
    if (t + 1 < NT) {
      STG(t + 1, cur ^ 1)        // full-K-tile prefetch lead
      wait_vm<8>();              // drain tile t, leave tile t+1 in flight
    } else {
      wait_vm<0>();
    }
    __builtin_amdgcn_sched_barrier(0);
    __builtin_amdgcn_s_barrier();
    __builtin_amdgcn_sched_barrier(0);

#pragma unroll
    for (int kk = 0; kk < 2; ++kk) {
      const int akc = (kk == 0) ? akc0 : akc1;
      short8 afk[4], bfk[4];
#pragma unroll
      for (int i = 0; i < 4; ++i)
        afk[i] = *(const short8*)&sA[cur][arow + i * 16 * 64 + akc];
#pragma unroll
      for (int j = 0; j < 4; ++j)
        bfk[j] = *(const short8*)&sB[cur][brow + j * 16 * 64 + akc];
      __builtin_amdgcn_s_setprio(1);
#pragma unroll
      for (int i = 0; i < 4; ++i)
#pragma unroll
        for (int j = 0; j < 4; ++j)
          acc[i][j] = __builtin_amdgcn_mfma_f32_16x16x32_bf16(
              afk[i], bfk[j], acc[i][j], 0, 0, 0);
      __builtin_amdgcn_s_setprio(0);
    }
    __builtin_amdgcn_s_barrier();      // reads(t) done (drained pre-MFMA);
    __builtin_amdgcn_sched_barrier(0); // next iter may restage buf[cur^1]
  }
#undef STG

#pragma unroll
  for (int i = 0; i < 4; ++i)
#pragma unroll
    for (int j = 0; j < 4; ++j)
#pragma unroll
      for (int r = 0; r < 4; ++r) {
        long row = m0 + wm * 64 + i * 16 + lg * 4 + r;
        long col = n0 + wn * 64 + j * 16 + l15;
        store_c(C, row * (long)N + col, acc[i][j][r]);
      }
}

// ---------------- RMSNorm + RoPE (in place on fused QKV, bf16) ----------------
__global__ __launch_bounds__(256) void k_normrope(u16* __restrict__ QKV,
                                                  const float* __restrict__ cosb,
                                                  const float* __restrict__ sinb,
                                                  const float* __restrict__ qw,
                                                  const float* __restrict__ kw) {
  const int lane = threadIdx.x & 63;
  const int w = threadIdx.x >> 6;
  int row = blockIdx.x * 4 + w;
  const int nQ = BATCH * S_LEN * NH;
  u16* p;
  const float* nw;
  int tok;
  float sc;
  if (row < nQ) {
    tok = row >> 4;
    int h = row & 15;
    p = QKV + (long)tok * QKVW + h * HD;
    nw = qw;
    sc = SCALE;
  } else {
    int r2 = row - nQ;
    tok = r2 >> 3;
    int h = r2 & 7;
    p = QKV + (long)tok * QKVW + 2048 + h * HD;
    nw = kw;
    sc = 1.0f;
  }
  float x0 = b2f(p[lane]);
  float x1 = b2f(p[lane + 64]);
  float ss = x0 * x0 + x1 * x1;
#pragma unroll
  for (int mk = 1; mk < 64; mk <<= 1) ss += __shfl_xor(ss, mk, 64);
  float rinv = rsqrtf(ss * (1.0f / 128.0f) + 1e-6f);
  float y0 = x0 * rinv * nw[lane];
  float y1 = x1 * rinv * nw[lane + 64];
  const float* cp = cosb + (long)tok * HD;
  const float* sp = sinb + (long)tok * HD;
  float o0 = (y0 * cp[lane] - y1 * sp[lane]) * sc;
  float o1 = (y1 * cp[lane + 64] + y0 * sp[lane + 64]) * sc;
  p[lane] = f2b(o0);
  p[lane + 64] = f2b(o1);
}

// ---------------- Flash attention (unchanged) ----------------
__global__ __launch_bounds__(256, 2) void k_attn(const u16* __restrict__ QKV,
                                                 u16* __restrict__ AO) {
  __shared__ u16 sK[64 * 128];
  __shared__ u16 sVT[64 * 128];
  const int tid = threadIdx.x;
  const int lane = tid & 63;
  const int l31 = lane & 31;
  const int hi = lane >> 5;
  const int w = tid >> 6;
  const int q0 = blockIdx.x * 128;
  const int h = blockIdx.y;
  const int b = blockIdx.z;
  const int kvh = h >> 1;
  const int qw0 = q0 + w * 32;
  const int iq = qw0 + l31;

  const long tokbase = (long)b * S_LEN;
  const u16* Qrow = QKV + (tokbase + qw0 + l31) * QKVW + h * HD;
  short8 qf[8];
#pragma unroll
  for (int dt = 0; dt < 8; ++dt) qf[dt] = *(const short8*)(Qrow + dt * 16 + hi * 8);

  f32x16 o[4];
#pragma unroll
  for (int n = 0; n < 4; ++n)
#pragma unroll
    for (int r = 0; r < 16; ++r) o[n][r] = 0.f;
  float m = 0.f, lsum = 0.f;

  const u16* Kbase = QKV + tokbase * QKVW + 2048 + kvh * HD;
  const u16* Vbase = QKV + tokbase * QKVW + 3072 + kvh * HD;

  int kc_row[4], kc_off[4];
  u16* kc_dst[4];
#pragma unroll
  for (int i = 0; i < 4; ++i) {
    const int c = tid + 256 * i;
    kc_row[i] = c >> 4;
    kc_off[i] = (((c & 15) ^ ((c >> 4) & 7))) * 8;
    kc_dst[i] = &sK[c * 8];
  }
  const int rp = tid & 31;
  const int dc0 = tid >> 5;
  const int rg_st = rp >> 2;

  int t_lo = q0 - (WINDOW - 1);
  t_lo = (t_lo < 0 ? 0 : t_lo) >> 6;
  const int t_hi = (q0 + 127) >> 6;

  for (int t = t_lo; t <= t_hi; ++t) {
    const int kv0 = t << 6;
#pragma unroll
    for (int i = 0; i < 4; ++i)
      gload_lds16(Kbase + (long)(kv0 + kc_row[i]) * QKVW + kc_off[i], kc_dst[i]);
#pragma unroll
    for (int i = 0; i < 2; ++i) {
      const int dc = dc0 + i * 8;
      const u16* vp = Vbase + (long)(kv0 + 2 * rp) * QKVW + dc * 8;
      short8 v0 = *(const short8*)vp;
      short8 v1 = *(const short8*)(vp + QKVW);
#pragma unroll
      for (int e = 0; e < 8; ++e) {
        const int d = dc * 8 + e;
        const int unit = d * 8 + (rg_st ^ (d & 7));
        ((u32*)sVT)[unit * 4 + (rp & 3)] = (u32)(u16)v0[e] | ((u32)(u16)v1[e] << 16);
      }
    }
    __syncthreads();

    const bool skipw = (kv0 > qw0 + 31) || (kv0 + 63 < qw0 - (WINDOW - 1));
    if (!skipw) {
      const bool full = (kv0 + 63 <= qw0) && ((qw0 + 31) - kv0 < WINDOW);
      f32x16 s0, s1;
#pragma unroll
      for (int r = 0; r < 16; ++r) { s0[r] = 0.f; s1[r] = 0.f; }
      const int rsw = l31 & 7;
#pragma unroll
      for (int dt = 0; dt < 8; ++dt) {
        const int ch = hi + 2 * dt;
        const short8 kf0 = *(const short8*)&sK[(l31 * 16 + (ch ^ rsw)) * 8];
        s0 = __builtin_amdgcn_mfma_f32_32x32x16_bf16(kf0, qf[dt], s0, 0, 0, 0);
        const short8 kf1 = *(const short8*)&sK[((l31 + 32) * 16 + (ch ^ rsw)) * 8];
        s1 = __builtin_amdgcn_mfma_f32_32x32x16_bf16(kf1, qf[dt], s1, 0, 0, 0);
      }
      float p[32];
#pragma unroll
      for (int r = 0; r < 16; ++r) { p[r] = s0[r]; p[16 + r] = s1[r]; }
      if (!full) {
#pragma unroll
        for (int r = 0; r < 32; ++r) {
          const int kk = kv0 + (r >> 4) * 32 + 4 * hi + (r & 3) + 8 * ((r >> 2) & 3);
          p[r] = ((u32)(iq - kk) < (u32)WINDOW) ? p[r] : -3.0e38f;
        }
      }
      float tm = p[0];
#pragma unroll
      for (int r = 1; r < 32; ++r) tm = fmaxf(tm, p[r]);
      tm = fmaxf(tm, __shfl_xor(tm, 32, 64));
      const float mn = fmaxf(m, tm);
      const float al = __expf(m - mn);
      m = mn;
      float rs = 0.f;
#pragma unroll
      for (int r = 0; r < 32; ++r) { p[r] = __expf(p[r] - mn); rs += p[r]; }
      rs += __shfl_xor(rs, 32, 64);
      lsum = lsum * al + rs;
#pragma unroll
      for (int n = 0; n < 4; ++n)
#pragma unroll
        for (int r = 0; r < 16; ++r) o[n][r] *= al;

      short8 pf[4];
#pragma unroll
      for (int ks = 0; ks < 4; ++ks) {
        const int bb = (ks >> 1) * 16 + (ks & 1) * 8;
        u32 a0 = pk_bf16(p[bb + 0], p[bb + 1]);
        u32 b0 = pk_bf16(p[bb + 4], p[bb + 5]);
        u32 a1 = pk_bf16(p[bb + 2], p[bb + 3]);
        u32 b1 = pk_bf16(p[bb + 6], p[bb + 7]);
        asm volatile("v_permlane32_swap_b32 %0, %1" : "+v"(a0), "+v"(b0));
        asm volatile("v_permlane32_swap_b32 %0, %1" : "+v"(a1), "+v"(b1));
        union { u32 u[4]; short8 s; } uu;
        uu.u[0] = a0; uu.u[1] = a1; uu.u[2] = b0; uu.u[3] = b1;
        pf[ks] = uu.s;
      }
#pragma unroll
      for (int dt = 0; dt < 4; ++dt) {
        const int d = l31 + 32 * dt;
        const int dsw = d & 7;
#pragma unroll
        for (int ks = 0; ks < 4; ++ks) {
          const int rg = ks * 2 + hi;
          const short8 vf = *(const short8*)&sVT[(d * 8 + (rg ^ dsw)) * 8];
          o[dt] = __builtin_amdgcn_mfma_f32_32x32x16_bf16(vf, pf[ks], o[dt], 0, 0, 0);
        }
      }
    }
    __syncthreads();
  }

  __syncthreads();
  float* R = ((float*)sK) + w * 1024;
  const float rl = 1.0f / lsum;
  const int half = hi;
#pragma unroll
  for (int dt = 0; dt < 4; ++dt) {
#pragma unroll
    for (int r = 0; r < 16; ++r) {
      const int dp = 4 * hi + (r & 3) + 8 * (r >> 2);
      R[dp * 32 + (l31 ^ (4 * (dp & 7)))] = o[dt][r] * rl;
    }
    __syncthreads();
    union { u16 hh[16]; short8 s[2]; } U;
#pragma unroll
    for (int j = 0; j < 16; ++j) {
      const int dp = half * 16 + j;
      U.hh[j] = f2b(R[dp * 32 + (l31 ^ (4 * (dp & 7)))]);
    }
    u16* dst = AO + (tokbase + q0 + w * 32 + l31) * (NH * HD) + h * HD + dt * 32 + half * 16;
    *(short8*)dst = U.s[0];
    *(short8*)(dst + 8) = U.s[1];
    __syncthreads();
  }
}

// ---------------- launch ----------------
extern "C" void kernel_launch(void* const* d_in, const int* in_sizes, int n_in,
                              void* d_out, int out_size, void* d_ws, size_t ws_size,
                              hipStream_t stream) {
  const float* hs   = (const float*)d_in[0];
  const float* cosb = (const float*)d_in[1];
  const float* sinb = (const float*)d_in[2];
  const float* Wq   = (const float*)d_in[3];
  const float* Wk   = (const float*)d_in[4];
  const float* Wv   = (const float*)d_in[5];
  const float* Wo   = (const float*)d_in[6];
  const float* qw   = (const float*)d_in[7];
  const float* kw   = (const float*)d_in[8];
  float* out = (float*)d_out;

  const long SZ_X  = (long)BATCH * S_LEN * HID;
  const long SZ_WQ = (long)NH * HD * HID;
  const long SZ_WK = (long)NKV * HD * HID;
  u16* Xb   = (u16*)d_ws;
  u16* Wqb  = Xb + SZ_X;
  u16* Wkb  = Wqb + SZ_WQ;
  u16* Wvb  = Wkb + SZ_WK;
  u16* Wob  = Wvb + SZ_WK;
  u16* QKVb = Wob + SZ_WQ;
  u16* AOb  = QKVb + (long)BATCH * S_LEN * QKVW;

  k_conv<<<2048, 256, 0, stream>>>(hs, Xb, (int)(SZ_X / 4));
  k_conv<<<1024, 256, 0, stream>>>(Wq, Wqb, (int)(SZ_WQ / 4));
  k_conv<<<512, 256, 0, stream>>>(Wk, Wkb, (int)(SZ_WK / 4));
  k_conv<<<512, 256, 0, stream>>>(Wv, Wvb, (int)(SZ_WK / 4));
  k_conv<<<1024, 256, 0, stream>>>(Wo, Wob, (int)(SZ_WQ / 4));

  // fused QKV projection: 4096 x 4096 x 2048, 1024 blocks (2/CU resident)
  k_gemm2b<u16><<<dim3(32, 32), 256, 0, stream>>>(
      Xb, Wqb, QKVb, BATCH * S_LEN, QKVW, HID);

  k_normrope<<<(BATCH * S_LEN * (NH + NKV)) / 4, 256, 0, stream>>>(QKVb, cosb, sinb, qw, kw);

  k_attn<<<dim3(S_LEN / 128, NH, BATCH), 256, 0, stream>>>(QKVb, AOb);

  // output projection: 4096 x 2048 x 2048, 512 blocks
  k_gemm2b<float><<<dim3(16, 32), 256, 0, stream>>>(
      AOb, Wob, out, BATCH * S_LEN, HID, HID);
}

// Round 9
// 211.005 us; speedup vs baseline: 1.0667x; 1.0125x over previous
//
#include <hip/hip_runtime.h>
#include <stdint.h>

#define S_LEN 2048
#define BATCH 2
#define HID 2048
#define NH 16
#define NKV 8
#define HD 128
#define WINDOW 1024
#define SCALE 0.08838834764831845f
#define QKVW 4096

typedef unsigned short u16;
typedef unsigned int u32;
typedef __attribute__((ext_vector_type(8))) short short8;
typedef __attribute__((ext_vector_type(4))) float f32x4;
typedef __attribute__((ext_vector_type(16))) float f32x16;
typedef __attribute__((ext_vector_type(4))) u16 u16x4;

__device__ __forceinline__ u16 f2b(float f) {
  u32 u = __builtin_bit_cast(u32, f);
  return (u16)((u + 0x7fffu + ((u >> 16) & 1u)) >> 16);
}
__device__ __forceinline__ float b2f(u16 h) {
  u32 u = ((u32)h) << 16;
  return __builtin_bit_cast(float, u);
}
__device__ __forceinline__ u32 pk_bf16(float a, float b) {
  u32 d;
  asm("v_cvt_pk_bf16_f32 %0, %1, %2" : "=v"(d) : "v"(a), "v"(b));
  return d;
}

__device__ __forceinline__ void gload_lds16(const u16* g, u16* l) {
  __builtin_amdgcn_global_load_lds(
      (const __attribute__((address_space(1))) u32*)g,
      (__attribute__((address_space(3))) u32*)l, 16, 0, 0);
}

template <int N>
__device__ __forceinline__ void wait_vm() {
  if constexpr (N == 0) asm volatile("s_waitcnt vmcnt(0)" ::: "memory");
  else if constexpr (N == 6) asm volatile("s_waitcnt vmcnt(6)" ::: "memory");
  else if constexpr (N == 8) asm volatile("s_waitcnt vmcnt(8)" ::: "memory");
}

// ---------------- f32 -> bf16 convert ----------------
__global__ __launch_bounds__(256) void k_conv(const float* __restrict__ src,
                                              u16* __restrict__ dst, int n4) {
  int i = blockIdx.x * blockDim.x + threadIdx.x;
  int st = gridDim.x * blockDim.x;
  for (; i < n4; i += st) {
    f32x4 v = ((const f32x4*)src)[i];
    u16x4 o;
    o[0] = f2b(v[0]); o[1] = f2b(v[1]); o[2] = f2b(v[2]); o[3] = f2b(v[3]);
    ((u16x4*)dst)[i] = o;
  }
}

__device__ __forceinline__ void store_c(u16* C, long idx, float v) { C[idx] = f2b(v); }
__device__ __forceinline__ void store_c(float* C, long idx, float v) { C[idx] = v; }

// ---- GEMM C = A*B^T : 128x256 block, 4 waves of 128x64, BK=32, 2 blocks/CU --
// LDS-traffic-ratio design: per CU per K-tile reads 96 KB + gload writes 48 KB
// (~1730 cyc @85 B/cyc) vs 1030 cyc MFMA -> ~60% ceiling (round 8's 64x64-wave
// structure: 256 KB -> 34% ceiling, measured 33%). acc 8x4 f32x4 = 128 VGPR;
// 2 waves/SIMD at <=256 VGPR. Simple 2-barrier loop, 1-tile prefetch lead,
// counted vmcnt(6). Frag chunk-swizzle ch^((row>>2)&3): all 64 16B slots of a
// b128 wave-read are distinct & bank-uniform (conflict-free); staging source
// inverse-swizzled, LDS dst linear (rule 21).
template <typename OutT>
__global__ __launch_bounds__(256, 2) void k_gemmW(const u16* __restrict__ A,
                                                  const u16* __restrict__ B,
                                                  OutT* __restrict__ C,
                                                  int M, int N, int K) {
  __shared__ u16 sA[2][128 * 32];   // 8 KB per buf
  __shared__ u16 sB[2][256 * 32];   // 16 KB per buf  -> 48 KB total
  const int tid = threadIdx.x;
  const int lane = tid & 63;
  const int w = tid >> 6;           // wave = n-quadrant (0..3)
  const int l15 = lane & 15;
  const int lg = lane >> 4;

  const int gx = gridDim.x;                 // N / 256
  const int nwg = gx * gridDim.y;
  const int flat = blockIdx.y * gx + blockIdx.x;
  const int tile = (flat & 7) * (nwg >> 3) + (flat >> 3);
  const long m0 = (long)(tile / gx) * 128;
  const long n0 = (long)(tile % gx) * 256;

  const u16* Abase = A + m0 * K;
  const u16* Bbase = B + n0 * K;

  // staging: 16B chunks; chunk c -> row = c>>2, ch = c&3 (rows are 64B = 4 chunks)
  // global source chunk = ch ^ ((row>>2)&3)  (inverse of the read swizzle)
  int aOff[2], aDst[2], bOff[4], bDst[4];
#pragma unroll
  for (int i = 0; i < 2; ++i) {
    const int c = tid + i * 256;            // 512 A-chunks
    const int row = c >> 2, ch = c & 3;
    aOff[i] = row * K + (ch ^ ((row >> 2) & 3)) * 8;
    aDst[i] = c * 8;
  }
#pragma unroll
  for (int i = 0; i < 4; ++i) {
    const int c = tid + i * 256;            // 1024 B-chunks
    const int row = c >> 2, ch = c & 3;
    bOff[i] = row * K + (ch ^ ((row >> 2) & 3)) * 8;
    bDst[i] = c * 8;
  }

  f32x4 acc[8][4];
  const f32x4 z4 = {0.f, 0.f, 0.f, 0.f};
#pragma unroll
  for (int i = 0; i < 8; ++i)
#pragma unroll
    for (int j = 0; j < 4; ++j) acc[i][j] = z4;

  // fragment read: chunk = lg ^ ((row>>2)&3); row = *+l15 -> (row>>2)&3 = (l15>>2)&3
  const int chsw = (lg ^ ((l15 >> 2) & 3)) * 8;
  const int brow0 = w * 64;

  const int NT = K >> 5;            // BK = 32

#define STG(KT, BUF)                                                    \
  _Pragma("unroll") for (int i_ = 0; i_ < 2; ++i_)                      \
      gload_lds16(Abase + aOff[i_] + (KT) * 32, &sA[BUF][aDst[i_]]);    \
  _Pragma("unroll") for (int i_ = 0; i_ < 4; ++i_)                      \
      gload_lds16(Bbase + bOff[i_] + (KT) * 32, &sB[BUF][bDst[i_]]);

  STG(0, 0)                         // prologue

  for (int t = 0; t < NT; ++t) {
    const int cur = t & 1;
    if (t + 1 < NT) {
      STG(t + 1, cur ^ 1)
      wait_vm<6>();                 // drain tile t, leave t+1's 6 loads in flight
    } else {
      wait_vm<0>();
    }
    __builtin_amdgcn_sched_barrier(0);
    __builtin_amdgcn_s_barrier();
    __builtin_amdgcn_sched_barrier(0);

    short8 af[8], bf[4];
#pragma unroll
    for (int i = 0; i < 8; ++i)
      af[i] = *(const short8*)&sA[cur][(i * 16 + l15) * 32 + chsw];
#pragma unroll
    for (int j = 0; j < 4; ++j)
      bf[j] = *(const short8*)&sB[cur][(brow0 + j * 16 + l15) * 32 + chsw];
    __builtin_amdgcn_s_setprio(1);
#pragma unroll
    for (int i = 0; i < 8; ++i)
#pragma unroll
      for (int j = 0; j < 4; ++j)
        acc[i][j] = __builtin_amdgcn_mfma_f32_16x16x32_bf16(
            af[i], bf[j], acc[i][j], 0, 0, 0);
    __builtin_amdgcn_s_setprio(0);

    __builtin_amdgcn_s_barrier();
    __builtin_amdgcn_sched_barrier(0);
  }
#undef STG

#pragma unroll
  for (int i = 0; i < 8; ++i)
#pragma unroll
    for (int j = 0; j < 4; ++j)
#pragma unroll
      for (int r = 0; r < 4; ++r) {
        long row = m0 + i * 16 + lg * 4 + r;
        long col = n0 + w * 64 + j * 16 + l15;
        store_c(C, row * (long)N + col, acc[i][j][r]);
      }
}

// ---- GEMM (round-8 structure, kept for Wo) : 128x128, BK=64, 2 blocks/CU ----
template <typename OutT>
__global__ __launch_bounds__(256, 2) void k_gemm2b(const u16* __restrict__ A,
                                                   const u16* __restrict__ B,
                                                   OutT* __restrict__ C,
                                                   int M, int N, int K) {
  __shared__ u16 sA[2][128 * 64];
  __shared__ u16 sB[2][128 * 64];
  const int tid = threadIdx.x;
  const int lane = tid & 63;
  const int w = tid >> 6;
  const int l15 = lane & 15;
  const int lg = lane >> 4;
  const int wm = w >> 1;
  const int wn = w & 1;
  const int sw = l15 & 7;

  const int gx = gridDim.x;
  const int nwg = gx * gridDim.y;
  const int flat = blockIdx.y * gx + blockIdx.x;
  const int tile = (flat & 7) * (nwg >> 3) + (flat >> 3);
  const long m0 = (long)(tile / gx) * 128;
  const long n0 = (long)(tile % gx) * 128;

  const u16* Abase = A + m0 * K;
  const u16* Bbase = B + n0 * K;

  int aOff[4], bOff[4], dstOff[4];
#pragma unroll
  for (int i = 0; i < 4; ++i) {
    const int c = tid + i * 256;
    const int row = c >> 3, chs = c & 7;
    const int scol = (chs ^ (row & 7)) * 8;
    aOff[i] = row * K + scol;
    bOff[i] = row * K + scol;
    dstOff[i] = c * 8;
  }

  f32x4 acc[4][4];
  const f32x4 z4 = {0.f, 0.f, 0.f, 0.f};
#pragma unroll
  for (int i = 0; i < 4; ++i)
#pragma unroll
    for (int j = 0; j < 4; ++j) acc[i][j] = z4;

  const int arow = (wm * 64 + l15) * 64;
  const int brow = (wn * 64 + l15) * 64;
  const int akc0 = (lg ^ sw) * 8;
  const int akc1 = ((4 + lg) ^ sw) * 8;

  const int NT = K >> 6;

#define STG(KT, BUF)                                                     \
  _Pragma("unroll") for (int i_ = 0; i_ < 4; ++i_)                       \
      gload_lds16(Abase + aOff[i_] + (KT) * 64, &sA[BUF][dstOff[i_]]);   \
  _Pragma("unroll") for (int i_ = 0; i_ < 4; ++i_)                       \
      gload_lds16(Bbase + bOff[i_] + (KT) * 64, &sB[BUF][dstOff[i_]]);

  STG(0, 0)

  for (int t = 0; t < NT; ++t) {
    const int cur = t & 1;
    if (t + 1 < NT) {
      STG(t + 1, cur ^ 1)
      wait_vm<8>();
    } else {
      wait_vm<0>();
    }
    __builtin_amdgcn_sched_barrier(0);
    __builtin_amdgcn_s_barrier();
    __builtin_amdgcn_sched_barrier(0);

#pragma unroll
    for (int kk = 0; kk < 2; ++kk) {
      const int akc = (kk == 0) ? akc0 : akc1;
      short8 afk[4], bfk[4];
#pragma unroll
      for (int i = 0; i < 4; ++i)
        afk[i] = *(const short8*)&sA[cur][arow + i * 16 * 64 + akc];
#pragma unroll
      for (int j = 0; j < 4; ++j)
        bfk[j] = *(const short8*)&sB[cur][brow + j * 16 * 64 + akc];
      __builtin_amdgcn_s_setprio(1);
#pragma unroll
      for (int i = 0; i < 4; ++i)
#pragma unroll
        for (int j = 0; j < 4; ++j)
          acc[i][j] = __builtin_amdgcn_mfma_f32_16x16x32_bf16(
              afk[i], bfk[j], acc[i][j], 0, 0, 0);
      __builtin_amdgcn_s_setprio(0);
    }
    __builtin_amdgcn_s_barrier();
    __builtin_amdgcn_sched_barrier(0);
  }
#undef STG

#pragma unroll
  for (int i = 0; i < 4; ++i)
#pragma unroll
    for (int j = 0; j < 4; ++j)
#pragma unroll
      for (int r = 0; r < 4; ++r) {
        long row = m0 + wm * 64 + i * 16 + lg * 4 + r;
        long col = n0 + wn * 64 + j * 16 + l15;
        store_c(C, row * (long)N + col, acc[i][j][r]);
      }
}

// ---------------- RMSNorm + RoPE (in place on fused QKV, bf16) ----------------
__global__ __launch_bounds__(256) void k_normrope(u16* __restrict__ QKV,
                                                  const float* __restrict__ cosb,
                                                  const float* __restrict__ sinb,
                                                  const float* __restrict__ qw,
                                                  const float* __restrict__ kw) {
  const int lane = threadIdx.x & 63;
  const int w = threadIdx.x >> 6;
  int row = blockIdx.x * 4 + w;
  const int nQ = BATCH * S_LEN * NH;
  u16* p;
  const float* nw;
  int tok;
  float sc;
  if (row < nQ) {
    tok = row >> 4;
    int h = row & 15;
    p = QKV + (long)tok * QKVW + h * HD;
    nw = qw;
    sc = SCALE;
  } else {
    int r2 = row - nQ;
    tok = r2 >> 3;
    int h = r2 & 7;
    p = QKV + (long)tok * QKVW + 2048 + h * HD;
    nw = kw;
    sc = 1.0f;
  }
  float x0 = b2f(p[lane]);
  float x1 = b2f(p[lane + 64]);
  float ss = x0 * x0 + x1 * x1;
#pragma unroll
  for (int mk = 1; mk < 64; mk <<= 1) ss += __shfl_xor(ss, mk, 64);
  float rinv = rsqrtf(ss * (1.0f / 128.0f) + 1e-6f);
  float y0 = x0 * rinv * nw[lane];
  float y1 = x1 * rinv * nw[lane + 64];
  const float* cp = cosb + (long)tok * HD;
  const float* sp = sinb + (long)tok * HD;
  float o0 = (y0 * cp[lane] - y1 * sp[lane]) * sc;
  float o1 = (y1 * cp[lane + 64] + y0 * sp[lane + 64]) * sc;
  p[lane] = f2b(o0);
  p[lane + 64] = f2b(o1);
}

// ---------------- Flash attention (unchanged) ----------------
__global__ __launch_bounds__(256, 2) void k_attn(const u16* __restrict__ QKV,
                                                 u16* __restrict__ AO) {
  __shared__ u16 sK[64 * 128];
  __shared__ u16 sVT[64 * 128];
  const int tid = threadIdx.x;
  const int lane = tid & 63;
  const int l31 = lane & 31;
  const int hi = lane >> 5;
  const int w = tid >> 6;
  const int q0 = blockIdx.x * 128;
  const int h = blockIdx.y;
  const int b = blockIdx.z;
  const int kvh = h >> 1;
  const int qw0 = q0 + w * 32;
  const int iq = qw0 + l31;

  const long tokbase = (long)b * S_LEN;
  const u16* Qrow = QKV + (tokbase + qw0 + l31) * QKVW + h * HD;
  short8 qf[8];
#pragma unroll
  for (int dt = 0; dt < 8; ++dt) qf[dt] = *(const short8*)(Qrow + dt * 16 + hi * 8);

  f32x16 o[4];
#pragma unroll
  for (int n = 0; n < 4; ++n)
#pragma unroll
    for (int r = 0; r < 16; ++r) o[n][r] = 0.f;
  float m = 0.f, lsum = 0.f;

  const u16* Kbase = QKV + tokbase * QKVW + 2048 + kvh * HD;
  const u16* Vbase = QKV + tokbase * QKVW + 3072 + kvh * HD;

  int kc_row[4], kc_off[4];
  u16* kc_dst[4];
#pragma unroll
  for (int i = 0; i < 4; ++i) {
    const int c = tid + 256 * i;
    kc_row[i] = c >> 4;
    kc_off[i] = (((c & 15) ^ ((c >> 4) & 7))) * 8;
    kc_dst[i] = &sK[c * 8];
  }
  const int rp = tid & 31;
  const int dc0 = tid >> 5;
  const int rg_st = rp >> 2;

  int t_lo = q0 - (WINDOW - 1);
  t_lo = (t_lo < 0 ? 0 : t_lo) >> 6;
  const int t_hi = (q0 + 127) >> 6;

  for (int t = t_lo; t <= t_hi; ++t) {
    const int kv0 = t << 6;
#pragma unroll
    for (int i = 0; i < 4; ++i)
      gload_lds16(Kbase + (long)(kv0 + kc_row[i]) * QKVW + kc_off[i], kc_dst[i]);
#pragma unroll
    for (int i = 0; i < 2; ++i) {
      const int dc = dc0 + i * 8;
      const u16* vp = Vbase + (long)(kv0 + 2 * rp) * QKVW + dc * 8;
      short8 v0 = *(const short8*)vp;
      short8 v1 = *(const short8*)(vp + QKVW);
#pragma unroll
      for (int e = 0; e < 8; ++e) {
        const int d = dc * 8 + e;
        const int unit = d * 8 + (rg_st ^ (d & 7));
        ((u32*)sVT)[unit * 4 + (rp & 3)] = (u32)(u16)v0[e] | ((u32)(u16)v1[e] << 16);
      }
    }
    __syncthreads();

    const bool skipw = (kv0 > qw0 + 31) || (kv0 + 63 < qw0 - (WINDOW - 1));
    if (!skipw) {
      const bool full = (kv0 + 63 <= qw0) && ((qw0 + 31) - kv0 < WINDOW);
      f32x16 s0, s1;
#pragma unroll
      for (int r = 0; r < 16; ++r) { s0[r] = 0.f; s1[r] = 0.f; }
      const int rsw = l31 & 7;
#pragma unroll
      for (int dt = 0; dt < 8; ++dt) {
        const int ch = hi + 2 * dt;
        const short8 kf0 = *(const short8*)&sK[(l31 * 16 + (ch ^ rsw)) * 8];
        s0 = __builtin_amdgcn_mfma_f32_32x32x16_bf16(kf0, qf[dt], s0, 0, 0, 0);
        const short8 kf1 = *(const short8*)&sK[((l31 + 32) * 16 + (ch ^ rsw)) * 8];
        s1 = __builtin_amdgcn_mfma_f32_32x32x16_bf16(kf1, qf[dt], s1, 0, 0, 0);
      }
      float p[32];
#pragma unroll
      for (int r = 0; r < 16; ++r) { p[r] = s0[r]; p[16 + r] = s1[r]; }
      if (!full) {
#pragma unroll
        for (int r = 0; r < 32; ++r) {
          const int kk = kv0 + (r >> 4) * 32 + 4 * hi + (r & 3) + 8 * ((r >> 2) & 3);
          p[r] = ((u32)(iq - kk) < (u32)WINDOW) ? p[r] : -3.0e38f;
        }
      }
      float tm = p[0];
#pragma unroll
      for (int r = 1; r < 32; ++r) tm = fmaxf(tm, p[r]);
      tm = fmaxf(tm, __shfl_xor(tm, 32, 64));
      const float mn = fmaxf(m, tm);
      const float al = __expf(m - mn);
      m = mn;
      float rs = 0.f;
#pragma unroll
      for (int r = 0; r < 32; ++r) { p[r] = __expf(p[r] - mn); rs += p[r]; }
      rs += __shfl_xor(rs, 32, 64);
      lsum = lsum * al + rs;
#pragma unroll
      for (int n = 0; n < 4; ++n)
#pragma unroll
        for (int r = 0; r < 16; ++r) o[n][r] *= al;

      short8 pf[4];
#pragma unroll
      for (int ks = 0; ks < 4; ++ks) {
        const int bb = (ks >> 1) * 16 + (ks & 1) * 8;
        u32 a0 = pk_bf16(p[bb + 0], p[bb + 1]);
        u32 b0 = pk_bf16(p[bb + 4], p[bb + 5]);
        u32 a1 = pk_bf16(p[bb + 2], p[bb + 3]);
        u32 b1 = pk_bf16(p[bb + 6], p[bb + 7]);
        asm volatile("v_permlane32_swap_b32 %0, %1" : "+v"(a0), "+v"(b0));
        asm volatile("v_permlane32_swap_b32 %0, %1" : "+v"(a1), "+v"(b1));
        union { u32 u[4]; short8 s; } uu;
        uu.u[0] = a0; uu.u[1] = a1; uu.u[2] = b0; uu.u[3] = b1;
        pf[ks] = uu.s;
      }
#pragma unroll
      for (int dt = 0; dt < 4; ++dt) {
        const int d = l31 + 32 * dt;
        const int dsw = d & 7;
#pragma unroll
        for (int ks = 0; ks < 4; ++ks) {
          const int rg = ks * 2 + hi;
          const short8 vf = *(const short8*)&sVT[(d * 8 + (rg ^ dsw)) * 8];
          o[dt] = __builtin_amdgcn_mfma_f32_32x32x16_bf16(vf, pf[ks], o[dt], 0, 0, 0);
        }
      }
    }
    __syncthreads();
  }

  __syncthreads();
  float* R = ((float*)sK) + w * 1024;
  const float rl = 1.0f / lsum;
  const int half = hi;
#pragma unroll
  for (int dt = 0; dt < 4; ++dt) {
#pragma unroll
    for (int r = 0; r < 16; ++r) {
      const int dp = 4 * hi + (r & 3) + 8 * (r >> 2);
      R[dp * 32 + (l31 ^ (4 * (dp & 7)))] = o[dt][r] * rl;
    }
    __syncthreads();
    union { u16 hh[16]; short8 s[2]; } U;
#pragma unroll
    for (int j = 0; j < 16; ++j) {
      const int dp = half * 16 + j;
      U.hh[j] = f2b(R[dp * 32 + (l31 ^ (4 * (dp & 7)))]);
    }
    u16* dst = AO + (tokbase + q0 + w * 32 + l31) * (NH * HD) + h * HD + dt * 32 + half * 16;
    *(short8*)dst = U.s[0];
    *(short8*)(dst + 8) = U.s[1];
    __syncthreads();
  }
}

// ---------------- launch ----------------
extern "C" void kernel_launch(void* const* d_in, const int* in_sizes, int n_in,
                              void* d_out, int out_size, void* d_ws, size_t ws_size,
                              hipStream_t stream) {
  const float* hs   = (const float*)d_in[0];
  const float* cosb = (const float*)d_in[1];
  const float* sinb = (const float*)d_in[2];
  const float* Wq   = (const float*)d_in[3];
  const float* Wk   = (const float*)d_in[4];
  const float* Wv   = (const float*)d_in[5];
  const float* Wo   = (const float*)d_in[6];
  const float* qw   = (const float*)d_in[7];
  const float* kw   = (const float*)d_in[8];
  float* out = (float*)d_out;

  const long SZ_X  = (long)BATCH * S_LEN * HID;
  const long SZ_WQ = (long)NH * HD * HID;
  const long SZ_WK = (long)NKV * HD * HID;
  u16* Xb   = (u16*)d_ws;
  u16* Wqb  = Xb + SZ_X;
  u16* Wkb  = Wqb + SZ_WQ;
  u16* Wvb  = Wkb + SZ_WK;
  u16* Wob  = Wvb + SZ_WK;
  u16* QKVb = Wob + SZ_WQ;
  u16* AOb  = QKVb + (long)BATCH * S_LEN * QKVW;

  k_conv<<<2048, 256, 0, stream>>>(hs, Xb, (int)(SZ_X / 4));
  k_conv<<<1024, 256, 0, stream>>>(Wq, Wqb, (int)(SZ_WQ / 4));
  k_conv<<<512, 256, 0, stream>>>(Wk, Wkb, (int)(SZ_WK / 4));
  k_conv<<<512, 256, 0, stream>>>(Wv, Wvb, (int)(SZ_WK / 4));
  k_conv<<<1024, 256, 0, stream>>>(Wo, Wob, (int)(SZ_WQ / 4));

  // fused QKV projection: 4096 x 4096 x 2048
  // k_gemmW: 128x256 tiles -> grid (4096/256) x (4096/128) = 16 x 32 = 512 blocks (2/CU)
  k_gemmW<u16><<<dim3(16, 32), 256, 0, stream>>>(
      Xb, Wqb, QKVb, BATCH * S_LEN, QKVW, HID);

  k_normrope<<<(BATCH * S_LEN * (NH + NKV)) / 4, 256, 0, stream>>>(QKVb, cosb, sinb, qw, kw);

  k_attn<<<dim3(S_LEN / 128, NH, BATCH), 256, 0, stream>>>(QKVb, AOb);

  // output projection: 4096 x 2048 x 2048, 128x128 tiles, 512 blocks (2/CU)
  k_gemm2b<float><<<dim3(16, 32), 256, 0, stream>>>(
      AOb, Wob, out, BATCH * S_LEN, HID, HID);
}